// Round 1
// baseline (1193.468 us; speedup 1.0000x reference)
//
#include <hip/hip_runtime.h>
#include <math.h>

#define NB 8
#define NC 64
#define NH 128
#define NW 128
#define NS 119
#define NPIX 113288   // 8*119*119

__device__ __forceinline__ float gelu_f(float v) {
    return 0.5f * v * (1.0f + erff(v * 0.70710678118654752f));
}

// ---------------- trig table: trig[t] = (cos, sin)(2*pi*t/128) ----------------
__global__ void __launch_bounds__(128) k_trig(float2* __restrict__ trig) {
    int t = threadIdx.x;
    double a = (double)t * (3.14159265358979323846 / 64.0);
    trig[t] = make_float2((float)cos(a), (float)sin(a));
}

// ---------------- fc0 + grid concat + transpose + zero pad ----------------
// out h[b][c][r][w], 128x128, zeros in pad region
__global__ void __launch_bounds__(256) k_fc0(const float* __restrict__ x,
                                             const float* __restrict__ w,
                                             const float* __restrict__ bia,
                                             float* __restrict__ h) {
    __shared__ float sw[320];
    __shared__ float sb[64];
    int t = threadIdx.x;
    for (int u = t; u < 320; u += 256) sw[u] = w[u];
    if (t < 64) sb[t] = bia[t];
    __syncthreads();
    int p = blockIdx.x * 256 + t;            // 0 .. 131071
    int b = p >> 14;
    int rem = p & 16383;
    int r = rem >> 7, wc = rem & 127;
    float v0 = 0.f, v1 = 0.f, v2 = 0.f, gx = 0.f, gy = 0.f;
    bool inside = (r < NS) && (wc < NS);
    if (inside) {
        const float* xp = x + ((size_t)(b * NS + r) * NS + wc) * 3;
        v0 = xp[0]; v1 = xp[1]; v2 = xp[2];
        gx = (float)r * (1.0f / 118.0f);
        gy = (float)wc * (1.0f / 118.0f);
    }
    float* hp = h + (size_t)b * NC * NH * NW + rem;
    for (int c = 0; c < 64; ++c) {
        float val = 0.f;
        if (inside) {
            const float* wr = sw + c * 5;
            val = v0 * wr[0] + v1 * wr[1] + v2 * wr[2] + gx * wr[3] + gy * wr[4] + sb[c];
        }
        hp[c * (NH * NW)] = val;
    }
}

// ---------------- CFT coeffs: cr[b][c][16] ----------------
// seg0 = rows 0..31, cols 0..31 ; seg1 = rows 0..31, cols 32..63
// coeff[seg*8+k] = (sum over rows, cols==k mod 8 of seg) / (128 * max(||seg||2, 1e-12))
__global__ void __launch_bounds__(256) k_cft(const float* __restrict__ h,
                                             float* __restrict__ cr) {
    __shared__ float sv[256][9];
    __shared__ float sq[256];
    int t = threadIdx.x;
    int bc = blockIdx.x;                      // b*64 + c
    int r = t >> 3;
    int g8 = (t & 7) << 3;                    // 0,8,...,56
    const float* rowp = h + ((size_t)bc * NH + r) * NW + g8;
    float s2 = 0.f;
#pragma unroll
    for (int j = 0; j < 8; ++j) {
        float v = rowp[j];
        sv[t][j] = v;
        s2 += v * v;
    }
    sq[t] = s2;
    __syncthreads();
    if (t < 16) {
        int half = t >> 3, k = t & 7;
        float sum = 0.f, ssq = 0.f;
        for (int gg = 0; gg < 32; ++gg) {
            int tt = gg * 8 + half * 4;
#pragma unroll
            for (int i = 0; i < 4; ++i) {
                sum += sv[tt + i][k];
                ssq += sq[tt + i];
            }
        }
        float norm = fmaxf(sqrtf(ssq), 1e-12f);
        cr[bc * 16 + t] = sum / (128.0f * norm);
    }
}

// ---------------- tiny MLP: corr[b][o] ----------------
__global__ void __launch_bounds__(1024) k_mlp(const float* __restrict__ cr,
                                              const float* __restrict__ g1w,
                                              const float* __restrict__ g1b,
                                              const float* __restrict__ g2w,
                                              const float* __restrict__ g2b,
                                              float* __restrict__ corr) {
    __shared__ float s_cr[1024];
    __shared__ float s_part[4][256];
    __shared__ float s_h[256];
    int b = blockIdx.x, t = threadIdx.x;
    s_cr[t] = cr[b * 1024 + t];
    __syncthreads();
    int j = t & 255, part = t >> 8;
    const float* wrow = g1w + (size_t)j * 2048 + part * 512;
    const float* cp = s_cr + part * 256;
    float acc = 0.f;
#pragma unroll 8
    for (int v = 0; v < 256; ++v) acc += cp[v] * wrow[2 * v];
    s_part[part][j] = acc;
    __syncthreads();
    if (t < 256) {
        float a = s_part[0][t] + s_part[1][t] + s_part[2][t] + s_part[3][t] + g1b[t];
        s_h[t] = gelu_f(a);
    }
    __syncthreads();
    if (t < 64) {
        float a2 = g2b[t];
        const float* w2row = g2w + t * 256;
#pragma unroll 8
        for (int v = 0; v < 256; ++v) a2 += s_h[v] * w2row[v];
        corr[b * 64 + t] = a2;
    }
}

// ---------------- DFT over W: T[row][ky] = sum_w h[row][w] e^{-2pi i ky w/128} ----------------
__global__ void __launch_bounds__(256) k_dftw(const float* __restrict__ h,
                                              float2* __restrict__ T,
                                              const float2* __restrict__ trig) {
    __shared__ __align__(16) float sx[16][132];
    __shared__ float2 st[128];
    int t = threadIdx.x;
    if (t < 128) st[t] = trig[t];
    size_t rbase = (size_t)blockIdx.x * 16;
    const float* src = h + rbase * NW;
    for (int u = t; u < 2048; u += 256) sx[u >> 7][u & 127] = src[u];
    __syncthreads();
    int r = t >> 4, ky = t & 15;
    float2 sv = st[ky];
    float sc = sv.x, ss = -sv.y;              // step = e^{-2pi i ky/128}
    float re = 0.f, im = 0.f;
    const float* xr = sx[r];
    for (int w0 = 0; w0 < 128; w0 += 16) {
        float2 bv = st[(ky * w0) & 127];
        float cc = bv.x, cs = -bv.y;          // e^{-2pi i ky w0/128}
#pragma unroll
        for (int j4 = 0; j4 < 4; ++j4) {
            float4 xv = *(const float4*)(xr + w0 + j4 * 4);
            re += xv.x * cc; im += xv.x * cs; { float nc = cc*sc - cs*ss; cs = cc*ss + cs*sc; cc = nc; }
            re += xv.y * cc; im += xv.y * cs; { float nc = cc*sc - cs*ss; cs = cc*ss + cs*sc; cc = nc; }
            re += xv.z * cc; im += xv.z * cs; { float nc = cc*sc - cs*ss; cs = cc*ss + cs*sc; cc = nc; }
            re += xv.w * cc; im += xv.w * cs; { float nc = cc*sc - cs*ss; cs = cc*ss + cs*sc; cc = nc; }
        }
    }
    T[(rbase + r) * 16 + ky] = make_float2(re, im);
}

// ---------------- DFT over H: xft[bc][m][ky] = sum_h T[bc][h][ky] e^{-2pi i kx(m) h/128} ----------------
__global__ void __launch_bounds__(512) k_dfth(const float2* __restrict__ T,
                                              float2* __restrict__ xft,
                                              const float2* __restrict__ trig) {
    __shared__ float2 s_T[2048];              // [h][ky]
    __shared__ float2 st[128];
    int t = threadIdx.x;
    if (t < 128) st[t] = trig[t];
    size_t base = (size_t)blockIdx.x * 2048;
    for (int u = t; u < 2048; u += 512) s_T[u] = T[base + u];
    __syncthreads();
    int m = t >> 4, ky = t & 15;
    int kx = (m < 16) ? m : (96 + m);
    float2 sv = st[kx];
    float sc = sv.x, ss = -sv.y;              // step = e^{-2pi i kx/128}
    float re = 0.f, im = 0.f;
    for (int h0 = 0; h0 < 128; h0 += 16) {
        float2 bv = st[(kx * h0) & 127];
        float cc = bv.x, cs = -bv.y;
#pragma unroll
        for (int j = 0; j < 16; ++j) {
            float2 Tv = s_T[(h0 + j) * 16 + ky];
            re += Tv.x * cc - Tv.y * cs;
            im += Tv.x * cs + Tv.y * cc;
            float nc = cc*sc - cs*ss; cs = cc*ss + cs*sc; cc = nc;
        }
    }
    xft[(size_t)blockIdx.x * 512 + m * 16 + ky] = make_float2(re, im);
}

// ---------------- spectral channel mix: F[b][ky][m][o] = sum_i xft[b][i][m][ky] * w(m)[i][o] ----------------
__global__ void __launch_bounds__(512) k_mix(const float2* __restrict__ xft,
                                             const float* __restrict__ w1r,
                                             const float* __restrict__ w1i,
                                             const float* __restrict__ w2r,
                                             const float* __restrict__ w2i,
                                             float2* __restrict__ F) {
    int rbid = blockIdx.x;
    int m = (rbid & 7) + 8 * ((rbid >> 3) & 3);   // XCD swizzle: same-m blocks share an XCD's L2
    int e = rbid >> 5;                             // ky
    __shared__ float2 s_w[64][64];                 // [i][o]
    __shared__ float2 s_x[8][64];                  // [b][i]
    int t = threadIdx.x;
    const float* wr; const float* wi; int mm;
    if (m < 16) { wr = w1r; wi = w1i; mm = m; } else { wr = w2r; wi = w2i; mm = m - 16; }
    int off = mm * 16 + e;
    for (int u = t; u < 4096; u += 512) {
        s_w[u >> 6][u & 63] = make_float2(wr[(u << 8) + off], wi[(u << 8) + off]);
    }
    {
        int bb = t >> 6, i = t & 63;
        s_x[bb][i] = xft[((size_t)(bb * 64 + i) * 32 + m) * 16 + e];
    }
    __syncthreads();
    int bb = t >> 6, o = t & 63;
    float re = 0.f, im = 0.f;
#pragma unroll 8
    for (int i = 0; i < 64; ++i) {
        float2 xv = s_x[bb][i];
        float2 wv = s_w[i][o];
        re += xv.x * wv.x - xv.y * wv.y;
        im += xv.x * wv.y + xv.y * wv.x;
    }
    F[((size_t)(bb * 16 + e) * 32 + m) * 64 + o] = make_float2(re, im);
}

// ---------------- inverse step A: G[b][h][ky][o] = sum_m F[b][ky][m][o] e^{+2pi i kx(m) h/128} ----------------
__global__ void __launch_bounds__(256) k_inva(const float2* __restrict__ F,
                                              float2* __restrict__ G,
                                              const float2* __restrict__ trig) {
    int blk = blockIdx.x;                     // (b, ky, hhalf)
    int hh = blk & 1;
    int ky = (blk >> 1) & 15;
    int b  = blk >> 5;
    __shared__ float2 s_f[32][64];
    __shared__ float2 s_t[128];
    int t = threadIdx.x;
    if (t < 128) s_t[t] = trig[t];
    for (int u = t; u < 2048; u += 256)
        s_f[u >> 6][u & 63] = F[(size_t)(b * 16 + ky) * 2048 + u];
    __syncthreads();
    int o = t & 63, hq = t >> 6;
    int h0 = hh * 64 + hq * 16;
    float accr[16], acci[16];
#pragma unroll
    for (int u = 0; u < 16; ++u) { accr[u] = 0.f; acci[u] = 0.f; }
    for (int m = 0; m < 32; ++m) {
        int kx = (m < 16) ? m : (96 + m);
        float2 f  = s_f[m][o];
        float2 stp = s_t[kx];                 // e^{+2pi i kx/128}
        float2 c0  = s_t[(kx * h0) & 127];    // e^{+2pi i kx h0/128}
        float zr = f.x * c0.x - f.y * c0.y;
        float zi = f.x * c0.y + f.y * c0.x;
#pragma unroll
        for (int u = 0; u < 16; ++u) {
            accr[u] += zr; acci[u] += zi;
            float nz = zr * stp.x - zi * stp.y;
            zi = zr * stp.y + zi * stp.x;
            zr = nz;
        }
    }
    size_t gbase = ((size_t)(b * 128 + h0) * 16 + ky) * 64 + o;
#pragma unroll
    for (int u = 0; u < 16; ++u)
        G[gbase + (size_t)u * 1024] = make_float2(accr[u], acci[u]);
}

// ---------------- inverse step B + 1x1 conv + corr + bias (+GELU) ----------------
__global__ void __launch_bounds__(128) k_invb(const float2* __restrict__ G,
                                              const float* __restrict__ hin,
                                              const float* __restrict__ cwl,
                                              const float* __restrict__ cbl,
                                              const float* __restrict__ corr,
                                              const float2* __restrict__ trig,
                                              float* __restrict__ hout,
                                              int do_gelu) {
    int blk = blockIdx.x;
    int b = blk >> 7, h = blk & 127;
    __shared__ __align__(16) float2 s_g[16][64];
    __shared__ __align__(16) float s_h[64][128];
    __shared__ __align__(16) float s_cw[64][64];   // [c][o]
    __shared__ float2 s_t[128];
    __shared__ float s_co[64];
    int t = threadIdx.x;
    if (t < 128) s_t[t] = trig[t];
    if (t < 64) s_co[t] = corr[b * 64 + t] + cbl[t];
    {
        float2* gp = &s_g[0][0];
        for (int u = t; u < 1024; u += 128)
            gp[u] = G[(size_t)(b * 128 + h) * 1024 + u];
    }
    for (int u = t; u < 8192; u += 128) {
        int c = u >> 7, w = u & 127;
        s_h[c][w] = hin[((size_t)(b * 64 + c) * 128 + h) * 128 + w];
    }
    for (int u = t; u < 4096; u += 128) {
        int c = u >> 6, o = u & 63;
        s_cw[c][o] = cwl[o * 64 + c];
    }
    __syncthreads();
    int ot = t >> 4, wt = t & 15;
    int o0 = ot * 8, w0 = wt * 8;
    float acc[8][8];
#pragma unroll
    for (int i = 0; i < 8; ++i)
#pragma unroll
        for (int j = 0; j < 8; ++j) acc[i][j] = 0.f;
    // inverse over ky
    for (int ky = 0; ky < 16; ++ky) {
        float gr[8], gi[8];
#pragma unroll
        for (int i = 0; i < 8; ++i) { float2 g = s_g[ky][o0 + i]; gr[i] = g.x; gi[i] = g.y; }
        float fs = (ky == 0) ? 1.f : 2.f;
#pragma unroll
        for (int j = 0; j < 8; ++j) {
            int idx = (ky * (w0 + j)) & 127;
            float2 cs = s_t[idx];
            float tc = fs * cs.x, ts = fs * cs.y;
#pragma unroll
            for (int i = 0; i < 8; ++i) acc[i][j] += gr[i] * tc - gi[i] * ts;
        }
    }
    const float invn = 1.0f / 16384.0f;
#pragma unroll
    for (int i = 0; i < 8; ++i)
#pragma unroll
        for (int j = 0; j < 8; ++j) acc[i][j] *= invn;
    // pointwise conv
    for (int c = 0; c < 64; ++c) {
        float cv[8], hv[8];
#pragma unroll
        for (int i = 0; i < 8; ++i) cv[i] = s_cw[c][o0 + i];
#pragma unroll
        for (int j = 0; j < 8; ++j) hv[j] = s_h[c][w0 + j];
#pragma unroll
        for (int i = 0; i < 8; ++i)
#pragma unroll
            for (int j = 0; j < 8; ++j) acc[i][j] += cv[i] * hv[j];
    }
#pragma unroll
    for (int i = 0; i < 8; ++i) {
        float co = s_co[o0 + i];
        float* outp = hout + ((size_t)(b * 64 + o0 + i) * 128 + h) * 128 + w0;
#pragma unroll
        for (int j = 0; j < 8; ++j) {
            float v = acc[i][j] + co;
            if (do_gelu) v = gelu_f(v);
            outp[j] = v;
        }
    }
}

// ---------------- head: crop + fc1 + GELU + fc2 ----------------
__global__ void __launch_bounds__(256) k_head(const float* __restrict__ h,
                                              const float* __restrict__ fc1w,
                                              const float* __restrict__ fc1b,
                                              const float* __restrict__ fc2w,
                                              const float* __restrict__ fc2b,
                                              float* __restrict__ out) {
    __shared__ __align__(16) float s_hx[64][132];
    __shared__ __align__(16) float s_w[64][128];   // [c][j]
    __shared__ float s_b1[128];
    __shared__ float s_w2[128];
    __shared__ float s_red[16][132];
    int t = threadIdx.x;
    int pbase = blockIdx.x * 128;
    if (t < 128) { s_b1[t] = fc1b[t]; s_w2[t] = fc2w[t]; }
    for (int u = t; u < 8192; u += 256) {
        int c = u >> 7, j = u & 127;
        s_w[c][j] = fc1w[j * 64 + c];
    }
    for (int u = t; u < 8192; u += 256) {
        int c = u >> 7, px = u & 127;
        int p = pbase + px;
        float v = 0.f;
        if (p < NPIX) {
            int b = p / 14161;
            int rem = p - b * 14161;
            int rr = rem / 119;
            int col = rem - rr * 119;
            v = h[((size_t)(b * 64 + c) * 128 + rr) * 128 + col];
        }
        s_hx[c][px] = v;
    }
    __syncthreads();
    int pt = t >> 4, jt = t & 15;
    int px0 = pt * 8, j0 = jt * 8;
    float acc[8][8];
#pragma unroll
    for (int i = 0; i < 8; ++i)
#pragma unroll
        for (int jj = 0; jj < 8; ++jj) acc[i][jj] = s_b1[j0 + jj];
    for (int c = 0; c < 64; ++c) {
        float hv[8], wv[8];
#pragma unroll
        for (int i = 0; i < 8; ++i) hv[i] = s_hx[c][px0 + i];
#pragma unroll
        for (int jj = 0; jj < 8; ++jj) wv[jj] = s_w[c][j0 + jj];
#pragma unroll
        for (int i = 0; i < 8; ++i)
#pragma unroll
            for (int jj = 0; jj < 8; ++jj) acc[i][jj] += hv[i] * wv[jj];
    }
#pragma unroll
    for (int i = 0; i < 8; ++i) {
        float o = 0.f;
#pragma unroll
        for (int jj = 0; jj < 8; ++jj) o += gelu_f(acc[i][jj]) * s_w2[j0 + jj];
        s_red[jt][px0 + i] = o;
    }
    __syncthreads();
    if (t < 128) {
        int p = pbase + t;
        if (p < NPIX) {
            float o = fc2b[0];
#pragma unroll
            for (int q = 0; q < 16; ++q) o += s_red[q][t];
            out[p] = o;
        }
    }
}

extern "C" void kernel_launch(void* const* d_in, const int* in_sizes, int n_in,
                              void* d_out, int out_size, void* d_ws, size_t ws_size,
                              hipStream_t stream) {
    const float* x    = (const float*)d_in[0];
    const float* sw1r = (const float*)d_in[1];
    const float* sw1i = (const float*)d_in[2];
    const float* sw2r = (const float*)d_in[3];
    const float* sw2i = (const float*)d_in[4];
    const float* g1w  = (const float*)d_in[5];
    const float* g1b  = (const float*)d_in[6];
    const float* g2w  = (const float*)d_in[7];
    const float* g2b  = (const float*)d_in[8];
    const float* cw   = (const float*)d_in[9];
    const float* cb   = (const float*)d_in[10];
    const float* fc0w = (const float*)d_in[11];
    const float* fc0b = (const float*)d_in[12];
    const float* fc1w = (const float*)d_in[13];
    const float* fc1b = (const float*)d_in[14];
    const float* fc2w = (const float*)d_in[15];
    const float* fc2b = (const float*)d_in[16];
    float* out = (float*)d_out;

    char* ws = (char*)d_ws;
    const size_t SZ_H   = (size_t)NB * NC * NH * NW * 4;      // 33554432
    const size_t SZ_T   = (size_t)NB * NC * NH * 16 * 8;      // 8388608
    const size_t SZ_XFT = (size_t)NB * NC * 32 * 16 * 8;      // 2097152
    const size_t SZ_F   = SZ_XFT;                             // 2097152
    const size_t SZ_G   = (size_t)NB * NH * 16 * 64 * 8;      // 8388608
    size_t off = 0;
    float2* trig = (float2*)(ws + off); off += 1024;
    float*  hA   = (float*)(ws + off);  off += SZ_H;
    float*  hB   = (float*)(ws + off);  off += SZ_H;
    float2* T    = (float2*)(ws + off); off += SZ_T;
    float2* xft  = (float2*)(ws + off); off += SZ_XFT;
    float2* F    = (float2*)(ws + off); off += SZ_F;
    float2* G    = (float2*)(ws + off); off += SZ_G;
    float*  cr   = (float*)(ws + off);  off += (size_t)NB * NC * 16 * 4;
    float*  corr = (float*)(ws + off);  off += (size_t)NB * 64 * 4;
    (void)ws_size; (void)in_sizes; (void)n_in; (void)out_size;

    k_trig<<<1, 128, 0, stream>>>(trig);
    k_fc0<<<512, 256, 0, stream>>>(x, fc0w, fc0b, hA);

    float* hcur = hA;
    float* hnxt = hB;
    for (int l = 0; l < 4; ++l) {
        const float* w1r = sw1r + (size_t)l * 1048576;
        const float* w1i = sw1i + (size_t)l * 1048576;
        const float* w2r = sw2r + (size_t)l * 1048576;
        const float* w2i = sw2i + (size_t)l * 1048576;
        const float* g1w_l = g1w + (size_t)l * 524288;
        const float* g1b_l = g1b + l * 256;
        const float* g2w_l = g2w + (size_t)l * 16384;
        const float* g2b_l = g2b + l * 64;
        const float* cw_l  = cw + (size_t)l * 4096;
        const float* cb_l  = cb + l * 64;

        k_cft<<<512, 256, 0, stream>>>(hcur, cr);
        k_mlp<<<8, 1024, 0, stream>>>(cr, g1w_l, g1b_l, g2w_l, g2b_l, corr);
        k_dftw<<<4096, 256, 0, stream>>>(hcur, T, trig);
        k_dfth<<<512, 512, 0, stream>>>(T, xft, trig);
        k_mix<<<512, 512, 0, stream>>>(xft, w1r, w1i, w2r, w2i, F);
        k_inva<<<256, 256, 0, stream>>>(F, G, trig);
        k_invb<<<1024, 128, 0, stream>>>(G, hcur, cw_l, cb_l, corr, trig, hnxt,
                                         (l < 3) ? 1 : 0);
        float* tmp = hcur; hcur = hnxt; hnxt = tmp;
    }
    // after 4 swaps, hcur == hA holds the final features
    k_head<<<886, 256, 0, stream>>>(hcur, fc1w, fc1b, fc2w, fc2b, out);
}

// Round 2
// 739.249 us; speedup vs baseline: 1.6144x; 1.6144x over previous
//
#include <hip/hip_runtime.h>
#include <math.h>

#define NB 8
#define NC 64
#define NH 128
#define NW 128
#define NS 119
#define NPIX 113288   // 8*119*119

__device__ __forceinline__ float gelu_f(float v) {
    return 0.5f * v * (1.0f + erff(v * 0.70710678118654752f));
}

// ---------------- trig table: trig[t] = (cos, sin)(2*pi*t/128) ----------------
__global__ void __launch_bounds__(128) k_trig(float2* __restrict__ trig) {
    int t = threadIdx.x;
    double a = (double)t * (3.14159265358979323846 / 64.0);
    trig[t] = make_float2((float)cos(a), (float)sin(a));
}

// ---------------- fc0 + grid concat + transpose + zero pad ----------------
__global__ void __launch_bounds__(256) k_fc0(const float* __restrict__ x,
                                             const float* __restrict__ w,
                                             const float* __restrict__ bia,
                                             float* __restrict__ h) {
    __shared__ float sw[320];
    __shared__ float sb[64];
    int t = threadIdx.x;
    for (int u = t; u < 320; u += 256) sw[u] = w[u];
    if (t < 64) sb[t] = bia[t];
    __syncthreads();
    int p = blockIdx.x * 256 + t;            // 0 .. 131071
    int b = p >> 14;
    int rem = p & 16383;
    int r = rem >> 7, wc = rem & 127;
    float v0 = 0.f, v1 = 0.f, v2 = 0.f, gx = 0.f, gy = 0.f;
    bool inside = (r < NS) && (wc < NS);
    if (inside) {
        const float* xp = x + ((size_t)(b * NS + r) * NS + wc) * 3;
        v0 = xp[0]; v1 = xp[1]; v2 = xp[2];
        gx = (float)r * (1.0f / 118.0f);
        gy = (float)wc * (1.0f / 118.0f);
    }
    float* hp = h + (size_t)b * NC * NH * NW + rem;
    for (int c = 0; c < 64; ++c) {
        float val = 0.f;
        if (inside) {
            const float* wr = sw + c * 5;
            val = v0 * wr[0] + v1 * wr[1] + v2 * wr[2] + gx * wr[3] + gy * wr[4] + sb[c];
        }
        hp[c * (NH * NW)] = val;
    }
}

// ---------------- CFT coeffs: cr[b][c][16] ----------------
__global__ void __launch_bounds__(256) k_cft(const float* __restrict__ h,
                                             float* __restrict__ cr) {
    __shared__ float sv[256][9];
    __shared__ float sq[256];
    int t = threadIdx.x;
    int bc = blockIdx.x;                      // b*64 + c
    int r = t >> 3;
    int g8 = (t & 7) << 3;                    // 0,8,...,56
    const float* rowp = h + ((size_t)bc * NH + r) * NW + g8;
    float s2 = 0.f;
#pragma unroll
    for (int j = 0; j < 8; ++j) {
        float v = rowp[j];
        sv[t][j] = v;
        s2 += v * v;
    }
    sq[t] = s2;
    __syncthreads();
    if (t < 16) {
        int half = t >> 3, k = t & 7;
        float sum = 0.f, ssq = 0.f;
        for (int gg = 0; gg < 32; ++gg) {
            int tt = gg * 8 + half * 4;
#pragma unroll
            for (int i = 0; i < 4; ++i) {
                sum += sv[tt + i][k];
                ssq += sq[tt + i];
            }
        }
        float norm = fmaxf(sqrtf(ssq), 1e-12f);
        cr[bc * 16 + t] = sum / (128.0f * norm);
    }
}

// ---------------- MLP stage 1: hmid[b][j] = gelu(sum_v cr[b][v]*g1w[j][2v] + g1b[j]) ----------------
// grid = 256 (one per j), block = 256
__global__ void __launch_bounds__(256) k_mlp1(const float* __restrict__ cr,
                                              const float* __restrict__ g1w,
                                              const float* __restrict__ g1b,
                                              float* __restrict__ hmid) {
    __shared__ float s_cr[8][1024];
    __shared__ float s_wave[4][8];
    int j = blockIdx.x;
    int t = threadIdx.x;
    {
        float* sp = &s_cr[0][0];
        for (int u = t; u < 8192; u += 256) sp[u] = cr[u];
    }
    const float* wrow = g1w + (size_t)j * 2048;
    int v0 = t * 4;
    float w0 = wrow[2 * v0], w1 = wrow[2 * v0 + 2], w2 = wrow[2 * v0 + 4], w3 = wrow[2 * v0 + 6];
    __syncthreads();
    float acc[8];
#pragma unroll
    for (int b = 0; b < 8; ++b) {
        const float* cp = s_cr[b] + v0;
        acc[b] = cp[0] * w0 + cp[1] * w1 + cp[2] * w2 + cp[3] * w3;
    }
    // wave reduce (64 lanes)
#pragma unroll
    for (int d = 32; d > 0; d >>= 1) {
#pragma unroll
        for (int b = 0; b < 8; ++b) acc[b] += __shfl_down(acc[b], d, 64);
    }
    int wv = t >> 6;
    if ((t & 63) == 0) {
#pragma unroll
        for (int b = 0; b < 8; ++b) s_wave[wv][b] = acc[b];
    }
    __syncthreads();
    if (t < 8) {
        float a = s_wave[0][t] + s_wave[1][t] + s_wave[2][t] + s_wave[3][t] + g1b[j];
        hmid[t * 256 + j] = gelu_f(a);
    }
}

// ---------------- MLP stage 2: corr[b][o] = sum_j hmid[b][j]*g2w[o][j] + g2b[o] ----------------
// grid = 64 (one per o), block = 256
__global__ void __launch_bounds__(256) k_mlp2(const float* __restrict__ hmid,
                                              const float* __restrict__ g2w,
                                              const float* __restrict__ g2b,
                                              float* __restrict__ corr) {
    __shared__ float s_h[2048];
    __shared__ float s_w[256];
    int o = blockIdx.x;
    int t = threadIdx.x;
    s_w[t] = g2w[o * 256 + t];
    for (int u = t; u < 2048; u += 256) s_h[u] = hmid[u];
    __syncthreads();
    int b = t >> 5, k = t & 31;
    const float* hp = s_h + b * 256 + k * 8;
    const float* wp = s_w + k * 8;
    float acc = 0.f;
#pragma unroll
    for (int i = 0; i < 8; ++i) acc += hp[i] * wp[i];
#pragma unroll
    for (int d = 16; d > 0; d >>= 1) acc += __shfl_down(acc, d, 32);
    if (k == 0) corr[b * 64 + o] = acc + g2b[o];
}

// ---------------- DFT over W ----------------
__global__ void __launch_bounds__(256) k_dftw(const float* __restrict__ h,
                                              float2* __restrict__ T,
                                              const float2* __restrict__ trig) {
    __shared__ __align__(16) float sx[16][132];
    __shared__ float2 st[128];
    int t = threadIdx.x;
    if (t < 128) st[t] = trig[t];
    size_t rbase = (size_t)blockIdx.x * 16;
    const float* src = h + rbase * NW;
    for (int u = t; u < 2048; u += 256) sx[u >> 7][u & 127] = src[u];
    __syncthreads();
    int r = t >> 4, ky = t & 15;
    float2 sv = st[ky];
    float sc = sv.x, ss = -sv.y;              // step = e^{-2pi i ky/128}
    float re = 0.f, im = 0.f;
    const float* xr = sx[r];
    for (int w0 = 0; w0 < 128; w0 += 16) {
        float2 bv = st[(ky * w0) & 127];
        float cc = bv.x, cs = -bv.y;          // e^{-2pi i ky w0/128}
#pragma unroll
        for (int j4 = 0; j4 < 4; ++j4) {
            float4 xv = *(const float4*)(xr + w0 + j4 * 4);
            re += xv.x * cc; im += xv.x * cs; { float nc = cc*sc - cs*ss; cs = cc*ss + cs*sc; cc = nc; }
            re += xv.y * cc; im += xv.y * cs; { float nc = cc*sc - cs*ss; cs = cc*ss + cs*sc; cc = nc; }
            re += xv.z * cc; im += xv.z * cs; { float nc = cc*sc - cs*ss; cs = cc*ss + cs*sc; cc = nc; }
            re += xv.w * cc; im += xv.w * cs; { float nc = cc*sc - cs*ss; cs = cc*ss + cs*sc; cc = nc; }
        }
    }
    T[(rbase + r) * 16 + ky] = make_float2(re, im);
}

// ---------------- DFT over H ----------------
__global__ void __launch_bounds__(512) k_dfth(const float2* __restrict__ T,
                                              float2* __restrict__ xft,
                                              const float2* __restrict__ trig) {
    __shared__ float2 s_T[2048];              // [h][ky]
    __shared__ float2 st[128];
    int t = threadIdx.x;
    if (t < 128) st[t] = trig[t];
    size_t base = (size_t)blockIdx.x * 2048;
    for (int u = t; u < 2048; u += 512) s_T[u] = T[base + u];
    __syncthreads();
    int m = t >> 4, ky = t & 15;
    int kx = (m < 16) ? m : (96 + m);
    float2 sv = st[kx];
    float sc = sv.x, ss = -sv.y;              // step = e^{-2pi i kx/128}
    float re = 0.f, im = 0.f;
    for (int h0 = 0; h0 < 128; h0 += 16) {
        float2 bv = st[(kx * h0) & 127];
        float cc = bv.x, cs = -bv.y;
#pragma unroll
        for (int j = 0; j < 16; ++j) {
            float2 Tv = s_T[(h0 + j) * 16 + ky];
            re += Tv.x * cc - Tv.y * cs;
            im += Tv.x * cs + Tv.y * cc;
            float nc = cc*sc - cs*ss; cs = cc*ss + cs*sc; cc = nc;
        }
    }
    xft[(size_t)blockIdx.x * 512 + m * 16 + ky] = make_float2(re, im);
}

// ---------------- spectral channel mix ----------------
__global__ void __launch_bounds__(512) k_mix(const float2* __restrict__ xft,
                                             const float* __restrict__ w1r,
                                             const float* __restrict__ w1i,
                                             const float* __restrict__ w2r,
                                             const float* __restrict__ w2i,
                                             float2* __restrict__ F) {
    int rbid = blockIdx.x;
    int m = (rbid & 7) + 8 * ((rbid >> 3) & 3);   // XCD swizzle
    int e = rbid >> 5;                             // ky
    __shared__ float2 s_w[64][64];                 // [i][o]
    __shared__ float2 s_x[8][64];                  // [b][i]
    int t = threadIdx.x;
    const float* wr; const float* wi; int mm;
    if (m < 16) { wr = w1r; wi = w1i; mm = m; } else { wr = w2r; wi = w2i; mm = m - 16; }
    int off = mm * 16 + e;
    for (int u = t; u < 4096; u += 512) {
        s_w[u >> 6][u & 63] = make_float2(wr[(u << 8) + off], wi[(u << 8) + off]);
    }
    {
        int bb = t >> 6, i = t & 63;
        s_x[bb][i] = xft[((size_t)(bb * 64 + i) * 32 + m) * 16 + e];
    }
    __syncthreads();
    int bb = t >> 6, o = t & 63;
    float re = 0.f, im = 0.f;
#pragma unroll 8
    for (int i = 0; i < 64; ++i) {
        float2 xv = s_x[bb][i];
        float2 wv = s_w[i][o];
        re += xv.x * wv.x - xv.y * wv.y;
        im += xv.x * wv.y + xv.y * wv.x;
    }
    F[((size_t)(bb * 16 + e) * 32 + m) * 64 + o] = make_float2(re, im);
}

// ---------------- inverse step A ----------------
__global__ void __launch_bounds__(256) k_inva(const float2* __restrict__ F,
                                              float2* __restrict__ G,
                                              const float2* __restrict__ trig) {
    int blk = blockIdx.x;                     // (b, ky, hhalf)
    int hh = blk & 1;
    int ky = (blk >> 1) & 15;
    int b  = blk >> 5;
    __shared__ float2 s_f[32][64];
    __shared__ float2 s_t[128];
    int t = threadIdx.x;
    if (t < 128) s_t[t] = trig[t];
    for (int u = t; u < 2048; u += 256)
        s_f[u >> 6][u & 63] = F[(size_t)(b * 16 + ky) * 2048 + u];
    __syncthreads();
    int o = t & 63, hq = t >> 6;
    int h0 = hh * 64 + hq * 16;
    float accr[16], acci[16];
#pragma unroll
    for (int u = 0; u < 16; ++u) { accr[u] = 0.f; acci[u] = 0.f; }
    for (int m = 0; m < 32; ++m) {
        int kx = (m < 16) ? m : (96 + m);
        float2 f  = s_f[m][o];
        float2 stp = s_t[kx];
        float2 c0  = s_t[(kx * h0) & 127];
        float zr = f.x * c0.x - f.y * c0.y;
        float zi = f.x * c0.y + f.y * c0.x;
#pragma unroll
        for (int u = 0; u < 16; ++u) {
            accr[u] += zr; acci[u] += zi;
            float nz = zr * stp.x - zi * stp.y;
            zi = zr * stp.y + zi * stp.x;
            zr = nz;
        }
    }
    size_t gbase = ((size_t)(b * 128 + h0) * 16 + ky) * 64 + o;
#pragma unroll
    for (int u = 0; u < 16; ++u)
        G[gbase + (size_t)u * 1024] = make_float2(accr[u], acci[u]);
}

// ---------------- inverse step B + 1x1 conv + corr + bias (+GELU) ----------------
__global__ void __launch_bounds__(128) k_invb(const float2* __restrict__ G,
                                              const float* __restrict__ hin,
                                              const float* __restrict__ cwl,
                                              const float* __restrict__ cbl,
                                              const float* __restrict__ corr,
                                              const float2* __restrict__ trig,
                                              float* __restrict__ hout,
                                              int do_gelu) {
    int blk = blockIdx.x;
    int b = blk >> 7, h = blk & 127;
    __shared__ __align__(16) float2 s_g[16][64];
    __shared__ __align__(16) float s_h[64][128];
    __shared__ __align__(16) float s_cw[64][64];   // [c][o]
    __shared__ float2 s_t[128];
    __shared__ float s_co[64];
    int t = threadIdx.x;
    if (t < 128) s_t[t] = trig[t];
    if (t < 64) s_co[t] = corr[b * 64 + t] + cbl[t];
    {
        float2* gp = &s_g[0][0];
        for (int u = t; u < 1024; u += 128)
            gp[u] = G[(size_t)(b * 128 + h) * 1024 + u];
    }
    for (int u = t; u < 8192; u += 128) {
        int c = u >> 7, w = u & 127;
        s_h[c][w] = hin[((size_t)(b * 64 + c) * 128 + h) * 128 + w];
    }
    for (int u = t; u < 4096; u += 128) {
        int c = u >> 6, o = u & 63;
        s_cw[c][o] = cwl[o * 64 + c];
    }
    __syncthreads();
    int ot = t >> 4, wt = t & 15;
    int o0 = ot * 8, w0 = wt * 8;
    float acc[8][8];
#pragma unroll
    for (int i = 0; i < 8; ++i)
#pragma unroll
        for (int j = 0; j < 8; ++j) acc[i][j] = 0.f;
    for (int ky = 0; ky < 16; ++ky) {
        float gr[8], gi[8];
#pragma unroll
        for (int i = 0; i < 8; ++i) { float2 g = s_g[ky][o0 + i]; gr[i] = g.x; gi[i] = g.y; }
        float fs = (ky == 0) ? 1.f : 2.f;
#pragma unroll
        for (int j = 0; j < 8; ++j) {
            int idx = (ky * (w0 + j)) & 127;
            float2 cs = s_t[idx];
            float tc = fs * cs.x, ts = fs * cs.y;
#pragma unroll
            for (int i = 0; i < 8; ++i) acc[i][j] += gr[i] * tc - gi[i] * ts;
        }
    }
    const float invn = 1.0f / 16384.0f;
#pragma unroll
    for (int i = 0; i < 8; ++i)
#pragma unroll
        for (int j = 0; j < 8; ++j) acc[i][j] *= invn;
    for (int c = 0; c < 64; ++c) {
        float cv[8], hv[8];
#pragma unroll
        for (int i = 0; i < 8; ++i) cv[i] = s_cw[c][o0 + i];
#pragma unroll
        for (int j = 0; j < 8; ++j) hv[j] = s_h[c][w0 + j];
#pragma unroll
        for (int i = 0; i < 8; ++i)
#pragma unroll
            for (int j = 0; j < 8; ++j) acc[i][j] += cv[i] * hv[j];
    }
#pragma unroll
    for (int i = 0; i < 8; ++i) {
        float co = s_co[o0 + i];
        float* outp = hout + ((size_t)(b * 64 + o0 + i) * 128 + h) * 128 + w0;
#pragma unroll
        for (int j = 0; j < 8; ++j) {
            float v = acc[i][j] + co;
            if (do_gelu) v = gelu_f(v);
            outp[j] = v;
        }
    }
}

// ---------------- head: crop + fc1 + GELU + fc2 ----------------
__global__ void __launch_bounds__(256) k_head(const float* __restrict__ h,
                                              const float* __restrict__ fc1w,
                                              const float* __restrict__ fc1b,
                                              const float* __restrict__ fc2w,
                                              const float* __restrict__ fc2b,
                                              float* __restrict__ out) {
    __shared__ __align__(16) float s_hx[64][132];
    __shared__ __align__(16) float s_w[64][128];   // [c][j]
    __shared__ float s_b1[128];
    __shared__ float s_w2[128];
    __shared__ float s_red[16][132];
    int t = threadIdx.x;
    int pbase = blockIdx.x * 128;
    if (t < 128) { s_b1[t] = fc1b[t]; s_w2[t] = fc2w[t]; }
    for (int u = t; u < 8192; u += 256) {
        int c = u >> 7, j = u & 127;
        s_w[c][j] = fc1w[j * 64 + c];
    }
    for (int u = t; u < 8192; u += 256) {
        int c = u >> 7, px = u & 127;
        int p = pbase + px;
        float v = 0.f;
        if (p < NPIX) {
            int b = p / 14161;
            int rem = p - b * 14161;
            int rr = rem / 119;
            int col = rem - rr * 119;
            v = h[((size_t)(b * 64 + c) * 128 + rr) * 128 + col];
        }
        s_hx[c][px] = v;
    }
    __syncthreads();
    int pt = t >> 4, jt = t & 15;
    int px0 = pt * 8, j0 = jt * 8;
    float acc[8][8];
#pragma unroll
    for (int i = 0; i < 8; ++i)
#pragma unroll
        for (int jj = 0; jj < 8; ++jj) acc[i][jj] = s_b1[j0 + jj];
    for (int c = 0; c < 64; ++c) {
        float hv[8], wv[8];
#pragma unroll
        for (int i = 0; i < 8; ++i) hv[i] = s_hx[c][px0 + i];
#pragma unroll
        for (int jj = 0; jj < 8; ++jj) wv[jj] = s_w[c][j0 + jj];
#pragma unroll
        for (int i = 0; i < 8; ++i)
#pragma unroll
            for (int jj = 0; jj < 8; ++jj) acc[i][jj] += hv[i] * wv[jj];
    }
#pragma unroll
    for (int i = 0; i < 8; ++i) {
        float o = 0.f;
#pragma unroll
        for (int jj = 0; jj < 8; ++jj) o += gelu_f(acc[i][jj]) * s_w2[j0 + jj];
        s_red[jt][px0 + i] = o;
    }
    __syncthreads();
    if (t < 128) {
        int p = pbase + t;
        if (p < NPIX) {
            float o = fc2b[0];
#pragma unroll
            for (int q = 0; q < 16; ++q) o += s_red[q][t];
            out[p] = o;
        }
    }
}

extern "C" void kernel_launch(void* const* d_in, const int* in_sizes, int n_in,
                              void* d_out, int out_size, void* d_ws, size_t ws_size,
                              hipStream_t stream) {
    const float* x    = (const float*)d_in[0];
    const float* sw1r = (const float*)d_in[1];
    const float* sw1i = (const float*)d_in[2];
    const float* sw2r = (const float*)d_in[3];
    const float* sw2i = (const float*)d_in[4];
    const float* g1w  = (const float*)d_in[5];
    const float* g1b  = (const float*)d_in[6];
    const float* g2w  = (const float*)d_in[7];
    const float* g2b  = (const float*)d_in[8];
    const float* cw   = (const float*)d_in[9];
    const float* cb   = (const float*)d_in[10];
    const float* fc0w = (const float*)d_in[11];
    const float* fc0b = (const float*)d_in[12];
    const float* fc1w = (const float*)d_in[13];
    const float* fc1b = (const float*)d_in[14];
    const float* fc2w = (const float*)d_in[15];
    const float* fc2b = (const float*)d_in[16];
    float* out = (float*)d_out;

    char* ws = (char*)d_ws;
    const size_t SZ_H   = (size_t)NB * NC * NH * NW * 4;      // 33554432
    const size_t SZ_T   = (size_t)NB * NC * NH * 16 * 8;      // 8388608
    const size_t SZ_XFT = (size_t)NB * NC * 32 * 16 * 8;      // 2097152
    const size_t SZ_F   = SZ_XFT;                             // 2097152
    const size_t SZ_G   = (size_t)NB * NH * 16 * 64 * 8;      // 8388608
    size_t off = 0;
    float2* trig = (float2*)(ws + off); off += 1024;
    float*  hA   = (float*)(ws + off);  off += SZ_H;
    float*  hB   = (float*)(ws + off);  off += SZ_H;
    float2* T    = (float2*)(ws + off); off += SZ_T;
    float2* xft  = (float2*)(ws + off); off += SZ_XFT;
    float2* F    = (float2*)(ws + off); off += SZ_F;
    float2* G    = (float2*)(ws + off); off += SZ_G;
    float*  cr   = (float*)(ws + off);  off += (size_t)NB * NC * 16 * 4;
    float*  hmid = (float*)(ws + off);  off += (size_t)NB * 256 * 4;
    float*  corr = (float*)(ws + off);  off += (size_t)NB * 64 * 4;
    (void)ws_size; (void)in_sizes; (void)n_in; (void)out_size;

    k_trig<<<1, 128, 0, stream>>>(trig);
    k_fc0<<<512, 256, 0, stream>>>(x, fc0w, fc0b, hA);

    float* hcur = hA;
    float* hnxt = hB;
    for (int l = 0; l < 4; ++l) {
        const float* w1r = sw1r + (size_t)l * 1048576;
        const float* w1i = sw1i + (size_t)l * 1048576;
        const float* w2r = sw2r + (size_t)l * 1048576;
        const float* w2i = sw2i + (size_t)l * 1048576;
        const float* g1w_l = g1w + (size_t)l * 524288;
        const float* g1b_l = g1b + l * 256;
        const float* g2w_l = g2w + (size_t)l * 16384;
        const float* g2b_l = g2b + l * 64;
        const float* cw_l  = cw + (size_t)l * 4096;
        const float* cb_l  = cb + l * 64;

        k_cft<<<512, 256, 0, stream>>>(hcur, cr);
        k_mlp1<<<256, 256, 0, stream>>>(cr, g1w_l, g1b_l, hmid);
        k_mlp2<<<64, 256, 0, stream>>>(hmid, g2w_l, g2b_l, corr);
        k_dftw<<<4096, 256, 0, stream>>>(hcur, T, trig);
        k_dfth<<<512, 512, 0, stream>>>(T, xft, trig);
        k_mix<<<512, 512, 0, stream>>>(xft, w1r, w1i, w2r, w2i, F);
        k_inva<<<256, 256, 0, stream>>>(F, G, trig);
        k_invb<<<1024, 128, 0, stream>>>(G, hcur, cw_l, cb_l, corr, trig, hnxt,
                                         (l < 3) ? 1 : 0);
        float* tmp = hcur; hcur = hnxt; hnxt = tmp;
    }
    // after 4 swaps, hcur == hA holds the final features
    k_head<<<886, 256, 0, stream>>>(hcur, fc1w, fc1b, fc2w, fc2b, out);
}

// Round 3
// 572.335 us; speedup vs baseline: 2.0853x; 1.2916x over previous
//
#include <hip/hip_runtime.h>
#include <math.h>

#define NB 8
#define NC 64
#define NH 128
#define NW 128
#define NS 119
#define NPIX 113288   // 8*119*119

__device__ __forceinline__ float gelu_f(float v) {
    return 0.5f * v * (1.0f + erff(v * 0.70710678118654752f));
}

// ---------------- trig table: trig[t] = (cos, sin)(2*pi*t/128) ----------------
__global__ void __launch_bounds__(128) k_trig(float2* __restrict__ trig) {
    int t = threadIdx.x;
    double a = (double)t * (3.14159265358979323846 / 64.0);
    trig[t] = make_float2((float)cos(a), (float)sin(a));
}

// ---------------- DFT-W matrix: wd[ky*128+w] = e^{-2pi i ky w/128} ----------------
__global__ void __launch_bounds__(128) k_tab(float2* __restrict__ wd) {
    int idx = blockIdx.x * 128 + threadIdx.x;   // 0..2047
    int ky = idx >> 7, w = idx & 127;
    int prod = (ky * w) & 127;
    double a = (double)prod * (3.14159265358979323846 / 64.0);
    wd[idx] = make_float2((float)cos(a), (float)(-sin(a)));
}

// ---------------- fc0 + grid concat + transpose + zero pad ----------------
__global__ void __launch_bounds__(256) k_fc0(const float* __restrict__ x,
                                             const float* __restrict__ w,
                                             const float* __restrict__ bia,
                                             float* __restrict__ h) {
    __shared__ float sw[320];
    __shared__ float sb[64];
    int t = threadIdx.x;
    for (int u = t; u < 320; u += 256) sw[u] = w[u];
    if (t < 64) sb[t] = bia[t];
    __syncthreads();
    int p = blockIdx.x * 256 + t;            // 0 .. 131071
    int b = p >> 14;
    int rem = p & 16383;
    int r = rem >> 7, wc = rem & 127;
    float v0 = 0.f, v1 = 0.f, v2 = 0.f, gx = 0.f, gy = 0.f;
    bool inside = (r < NS) && (wc < NS);
    if (inside) {
        const float* xp = x + ((size_t)(b * NS + r) * NS + wc) * 3;
        v0 = xp[0]; v1 = xp[1]; v2 = xp[2];
        gx = (float)r * (1.0f / 118.0f);
        gy = (float)wc * (1.0f / 118.0f);
    }
    float* hp = h + (size_t)b * NC * NH * NW + rem;
    for (int c = 0; c < 64; ++c) {
        float val = 0.f;
        if (inside) {
            const float* wr = sw + c * 5;
            val = v0 * wr[0] + v1 * wr[1] + v2 * wr[2] + gx * wr[3] + gy * wr[4] + sb[c];
        }
        hp[c * (NH * NW)] = val;
    }
}

// ---------------- CFT coeffs: cr[b][c][16] ----------------
__global__ void __launch_bounds__(256) k_cft(const float* __restrict__ h,
                                             float* __restrict__ cr) {
    __shared__ float sv[256][9];
    __shared__ float sq[256];
    int t = threadIdx.x;
    int bc = blockIdx.x;                      // b*64 + c
    int r = t >> 3;
    int g8 = (t & 7) << 3;                    // 0,8,...,56
    const float* rowp = h + ((size_t)bc * NH + r) * NW + g8;
    float s2 = 0.f;
#pragma unroll
    for (int j = 0; j < 8; ++j) {
        float v = rowp[j];
        sv[t][j] = v;
        s2 += v * v;
    }
    sq[t] = s2;
    __syncthreads();
    if (t < 16) {
        int half = t >> 3, k = t & 7;
        float sum = 0.f, ssq = 0.f;
        for (int gg = 0; gg < 32; ++gg) {
            int tt = gg * 8 + half * 4;
#pragma unroll
            for (int i = 0; i < 4; ++i) {
                sum += sv[tt + i][k];
                ssq += sq[tt + i];
            }
        }
        float norm = fmaxf(sqrtf(ssq), 1e-12f);
        cr[bc * 16 + t] = sum / (128.0f * norm);
    }
}

// ---------------- MLP stage 1 ----------------
__global__ void __launch_bounds__(256) k_mlp1(const float* __restrict__ cr,
                                              const float* __restrict__ g1w,
                                              const float* __restrict__ g1b,
                                              float* __restrict__ hmid) {
    __shared__ float s_cr[8][1024];
    __shared__ float s_wave[4][8];
    int j = blockIdx.x;
    int t = threadIdx.x;
    {
        float* sp = &s_cr[0][0];
        for (int u = t; u < 8192; u += 256) sp[u] = cr[u];
    }
    const float* wrow = g1w + (size_t)j * 2048;
    int v0 = t * 4;
    float w0 = wrow[2 * v0], w1 = wrow[2 * v0 + 2], w2 = wrow[2 * v0 + 4], w3 = wrow[2 * v0 + 6];
    __syncthreads();
    float acc[8];
#pragma unroll
    for (int b = 0; b < 8; ++b) {
        const float* cp = s_cr[b] + v0;
        acc[b] = cp[0] * w0 + cp[1] * w1 + cp[2] * w2 + cp[3] * w3;
    }
#pragma unroll
    for (int d = 32; d > 0; d >>= 1) {
#pragma unroll
        for (int b = 0; b < 8; ++b) acc[b] += __shfl_down(acc[b], d, 64);
    }
    int wv = t >> 6;
    if ((t & 63) == 0) {
#pragma unroll
        for (int b = 0; b < 8; ++b) s_wave[wv][b] = acc[b];
    }
    __syncthreads();
    if (t < 8) {
        float a = s_wave[0][t] + s_wave[1][t] + s_wave[2][t] + s_wave[3][t] + g1b[j];
        hmid[t * 256 + j] = gelu_f(a);
    }
}

// ---------------- MLP stage 2 ----------------
__global__ void __launch_bounds__(256) k_mlp2(const float* __restrict__ hmid,
                                              const float* __restrict__ g2w,
                                              const float* __restrict__ g2b,
                                              float* __restrict__ corr) {
    __shared__ float s_h[2048];
    __shared__ float s_w[256];
    int o = blockIdx.x;
    int t = threadIdx.x;
    s_w[t] = g2w[o * 256 + t];
    for (int u = t; u < 2048; u += 256) s_h[u] = hmid[u];
    __syncthreads();
    int b = t >> 5, k = t & 31;
    const float* hp = s_h + b * 256 + k * 8;
    const float* wp = s_w + k * 8;
    float acc = 0.f;
#pragma unroll
    for (int i = 0; i < 8; ++i) acc += hp[i] * wp[i];
#pragma unroll
    for (int d = 16; d > 0; d >>= 1) acc += __shfl_down(acc, d, 32);
    if (k == 0) corr[b * 64 + o] = acc + g2b[o];
}

// ---------------- DFT over W (LDS matrix version) ----------------
// block: 32 rows; thread (rp, ky) handles rows 2rp, 2rp+1
__global__ void __launch_bounds__(256) k_dftw(const float* __restrict__ h,
                                              float2* __restrict__ T,
                                              const float2* __restrict__ wd) {
    __shared__ __align__(16) float sx[32][140];
    __shared__ __align__(16) float2 sW[16][134];
    int t = threadIdx.x;
    size_t rbase = (size_t)blockIdx.x * 32;
    const float* src = h + rbase * NW;
    for (int u = t; u < 4096; u += 256) sx[u >> 7][u & 127] = src[u];
    for (int u = t; u < 2048; u += 256) sW[u >> 7][u & 127] = wd[u];
    __syncthreads();
    int rp = t >> 4, ky = t & 15;
    const float* xa = sx[2 * rp];
    const float* xb = sx[2 * rp + 1];
    const float2* wk = sW[ky];
    float rea = 0.f, ima = 0.f, reb = 0.f, imb = 0.f;
#pragma unroll 8
    for (int w0 = 0; w0 < 128; w0 += 4) {
        float4 a4 = *(const float4*)(xa + w0);
        float4 b4 = *(const float4*)(xb + w0);
        float4 w01 = *(const float4*)(wk + w0);       // (c0,s0,c1,s1)
        float4 w23 = *(const float4*)(wk + w0 + 2);   // (c2,s2,c3,s3)
        rea += a4.x * w01.x; ima += a4.x * w01.y;
        reb += b4.x * w01.x; imb += b4.x * w01.y;
        rea += a4.y * w01.z; ima += a4.y * w01.w;
        reb += b4.y * w01.z; imb += b4.y * w01.w;
        rea += a4.z * w23.x; ima += a4.z * w23.y;
        reb += b4.z * w23.x; imb += b4.z * w23.y;
        rea += a4.w * w23.z; ima += a4.w * w23.w;
        reb += b4.w * w23.z; imb += b4.w * w23.w;
    }
    T[(rbase + 2 * rp) * 16 + ky] = make_float2(rea, ima);
    T[(rbase + 2 * rp + 1) * 16 + ky] = make_float2(reb, imb);
}

// ---------------- DFT over H ----------------
__global__ void __launch_bounds__(512) k_dfth(const float2* __restrict__ T,
                                              float2* __restrict__ xft,
                                              const float2* __restrict__ trig) {
    __shared__ float2 s_T[2048];              // [h][ky]
    __shared__ float2 st[128];
    int t = threadIdx.x;
    if (t < 128) st[t] = trig[t];
    size_t base = (size_t)blockIdx.x * 2048;
    for (int u = t; u < 2048; u += 512) s_T[u] = T[base + u];
    __syncthreads();
    int m = t >> 4, ky = t & 15;
    int kx = (m < 16) ? m : (96 + m);
    float2 sv = st[kx];
    float sc = sv.x, ss = -sv.y;              // step = e^{-2pi i kx/128}
    float re = 0.f, im = 0.f;
    for (int h0 = 0; h0 < 128; h0 += 16) {
        float2 bv = st[(kx * h0) & 127];
        float cc = bv.x, cs = -bv.y;
#pragma unroll
        for (int j = 0; j < 16; ++j) {
            float2 Tv = s_T[(h0 + j) * 16 + ky];
            re += Tv.x * cc - Tv.y * cs;
            im += Tv.x * cs + Tv.y * cc;
            float nc = cc*sc - cs*ss; cs = cc*ss + cs*sc; cc = nc;
        }
    }
    xft[(size_t)blockIdx.x * 512 + m * 16 + ky] = make_float2(re, im);
}

// ---------------- spectral channel mix ----------------
__global__ void __launch_bounds__(512) k_mix(const float2* __restrict__ xft,
                                             const float* __restrict__ w1r,
                                             const float* __restrict__ w1i,
                                             const float* __restrict__ w2r,
                                             const float* __restrict__ w2i,
                                             float2* __restrict__ F) {
    int rbid = blockIdx.x;
    int m = (rbid & 7) + 8 * ((rbid >> 3) & 3);   // XCD swizzle
    int e = rbid >> 5;                             // ky
    __shared__ float2 s_w[64][64];                 // [i][o]
    __shared__ float2 s_x[8][64];                  // [b][i]
    int t = threadIdx.x;
    const float* wr; const float* wi; int mm;
    if (m < 16) { wr = w1r; wi = w1i; mm = m; } else { wr = w2r; wi = w2i; mm = m - 16; }
    int off = mm * 16 + e;
    for (int u = t; u < 4096; u += 512) {
        s_w[u >> 6][u & 63] = make_float2(wr[(u << 8) + off], wi[(u << 8) + off]);
    }
    {
        int bb = t >> 6, i = t & 63;
        s_x[bb][i] = xft[((size_t)(bb * 64 + i) * 32 + m) * 16 + e];
    }
    __syncthreads();
    int bb = t >> 6, o = t & 63;
    float re = 0.f, im = 0.f;
#pragma unroll 8
    for (int i = 0; i < 64; ++i) {
        float2 xv = s_x[bb][i];
        float2 wv = s_w[i][o];
        re += xv.x * wv.x - xv.y * wv.y;
        im += xv.x * wv.y + xv.y * wv.x;
    }
    F[((size_t)(bb * 16 + e) * 32 + m) * 64 + o] = make_float2(re, im);
}

// ---------------- inverse step A ----------------
__global__ void __launch_bounds__(256) k_inva(const float2* __restrict__ F,
                                              float2* __restrict__ G,
                                              const float2* __restrict__ trig) {
    int blk = blockIdx.x;                     // (b, ky, hhalf)
    int hh = blk & 1;
    int ky = (blk >> 1) & 15;
    int b  = blk >> 5;
    __shared__ float2 s_f[32][64];
    __shared__ float2 s_t[128];
    int t = threadIdx.x;
    if (t < 128) s_t[t] = trig[t];
    for (int u = t; u < 2048; u += 256)
        s_f[u >> 6][u & 63] = F[(size_t)(b * 16 + ky) * 2048 + u];
    __syncthreads();
    int o = t & 63, hq = t >> 6;
    int h0 = hh * 64 + hq * 16;
    float accr[16], acci[16];
#pragma unroll
    for (int u = 0; u < 16; ++u) { accr[u] = 0.f; acci[u] = 0.f; }
    for (int m = 0; m < 32; ++m) {
        int kx = (m < 16) ? m : (96 + m);
        float2 f  = s_f[m][o];
        float2 stp = s_t[kx];
        float2 c0  = s_t[(kx * h0) & 127];
        float zr = f.x * c0.x - f.y * c0.y;
        float zi = f.x * c0.y + f.y * c0.x;
#pragma unroll
        for (int u = 0; u < 16; ++u) {
            accr[u] += zr; acci[u] += zi;
            float nz = zr * stp.x - zi * stp.y;
            zi = zr * stp.y + zi * stp.x;
            zr = nz;
        }
    }
    size_t gbase = ((size_t)(b * 128 + h0) * 16 + ky) * 64 + o;
#pragma unroll
    for (int u = 0; u < 16; ++u)
        G[gbase + (size_t)u * 1024] = make_float2(accr[u], acci[u]);
}

// ---------------- inverse step B + 1x1 conv + corr + bias (+GELU) ----------------
// 1024 blocks (b,h), 256 threads. Wave-uniform o-tile of 16, lanes span w.
__global__ void __launch_bounds__(256, 4) k_invb(const float2* __restrict__ G,
                                                 const float* __restrict__ hin,
                                                 const float* __restrict__ cwl,
                                                 const float* __restrict__ cbl,
                                                 const float* __restrict__ corr,
                                                 const float2* __restrict__ trig,
                                                 float* __restrict__ hout,
                                                 int do_gelu) {
    int blk = blockIdx.x;
    int b = blk >> 7, h = blk & 127;
    __shared__ __align__(16) float s_cwT[64][64];   // [c][o]
    __shared__ __align__(16) float2 s_g[16][64];    // [ky][o]
    __shared__ __align__(16) float s_h[16][128];    // chunk of 16 c
    __shared__ float2 s_t[128];
    __shared__ float s_co[64];
    int t = threadIdx.x;
    if (t < 128) s_t[t] = trig[t];
    if (t < 64) s_co[t] = corr[b * 64 + t] + cbl[t];
    for (int u = t; u < 4096; u += 256) s_cwT[u & 63][u >> 6] = cwl[u];  // u = o*64+c
    {
        const float2* gp = G + (size_t)(b * 128 + h) * 1024;
        for (int u = t; u < 1024; u += 256) s_g[u >> 6][u & 63] = gp[u];
    }
    __syncthreads();
    int ot2 = t >> 6;          // wave id 0..3 -> o0 = ot2*16 (wave-uniform)
    int wt6 = t & 63;          // lane -> w base
    int o0 = ot2 * 16;
    float acc[16][2];
#pragma unroll
    for (int i = 0; i < 16; ++i) { acc[i][0] = 0.f; acc[i][1] = 0.f; }
    // --- inverse DFT over ky: per-thread twiddle recurrence over ky ---
    float2 rw0 = s_t[wt6];          // e^{+2pi i w0/128}, w0 = wt6
    float2 rw1 = s_t[wt6 + 64];     // w1 = wt6+64
    float z0r = 1.f, z0i = 0.f, z1r = 1.f, z1i = 0.f;
    for (int ky = 0; ky < 16; ++ky) {
        float fs = (ky == 0) ? 1.f : 2.f;
        float tc0 = fs * z0r, ts0 = fs * z0i;
        float tc1 = fs * z1r, ts1 = fs * z1i;
        const float4* gk = (const float4*)(&s_g[ky][o0]);
#pragma unroll
        for (int i2 = 0; i2 < 8; ++i2) {
            float4 g2 = gk[i2];      // (gr[2i2], gi[2i2], gr[2i2+1], gi[2i2+1])
            acc[2*i2][0]   += g2.x * tc0 - g2.y * ts0;
            acc[2*i2][1]   += g2.x * tc1 - g2.y * ts1;
            acc[2*i2+1][0] += g2.z * tc0 - g2.w * ts0;
            acc[2*i2+1][1] += g2.z * tc1 - g2.w * ts1;
        }
        float nz0 = z0r * rw0.x - z0i * rw0.y; z0i = z0r * rw0.y + z0i * rw0.x; z0r = nz0;
        float nz1 = z1r * rw1.x - z1i * rw1.y; z1i = z1r * rw1.y + z1i * rw1.x; z1r = nz1;
    }
    const float invn = 1.0f / 16384.0f;
#pragma unroll
    for (int i = 0; i < 16; ++i) { acc[i][0] *= invn; acc[i][1] *= invn; }
    // --- pointwise conv, c-chunked staging ---
    for (int cc = 0; cc < 64; cc += 16) {
        __syncthreads();
        for (int u = t; u < 2048; u += 256) {
            int c = u >> 7, w = u & 127;
            s_h[c][w] = hin[((size_t)(b * 64 + cc + c) * 128 + h) * 128 + w];
        }
        __syncthreads();
        for (int c = 0; c < 16; ++c) {
            float hv0 = s_h[c][wt6];
            float hv1 = s_h[c][wt6 + 64];
            const float4* cwp = (const float4*)(&s_cwT[cc + c][o0]);
#pragma unroll
            for (int i4 = 0; i4 < 4; ++i4) {
                float4 cv = cwp[i4];
                acc[4*i4][0]   += cv.x * hv0; acc[4*i4][1]   += cv.x * hv1;
                acc[4*i4+1][0] += cv.y * hv0; acc[4*i4+1][1] += cv.y * hv1;
                acc[4*i4+2][0] += cv.z * hv0; acc[4*i4+2][1] += cv.z * hv1;
                acc[4*i4+3][0] += cv.w * hv0; acc[4*i4+3][1] += cv.w * hv1;
            }
        }
    }
#pragma unroll
    for (int i = 0; i < 16; ++i) {
        int o = o0 + i;
        float co = s_co[o];
        float* outp = hout + ((size_t)(b * 64 + o) * 128 + h) * 128;
        float v0 = acc[i][0] + co;
        float v1 = acc[i][1] + co;
        if (do_gelu) { v0 = gelu_f(v0); v1 = gelu_f(v1); }
        outp[wt6] = v0;
        outp[wt6 + 64] = v1;
    }
}

// ---------------- head: crop + fc1 + GELU + fc2 ----------------
__global__ void __launch_bounds__(256) k_head(const float* __restrict__ h,
                                              const float* __restrict__ fc1w,
                                              const float* __restrict__ fc1b,
                                              const float* __restrict__ fc2w,
                                              const float* __restrict__ fc2b,
                                              float* __restrict__ out) {
    __shared__ __align__(16) float s_hx[64][132];
    __shared__ __align__(16) float s_w[64][128];   // [c][j]
    __shared__ float s_b1[128];
    __shared__ float s_w2[128];
    __shared__ float s_red[16][132];
    int t = threadIdx.x;
    int pbase = blockIdx.x * 128;
    if (t < 128) { s_b1[t] = fc1b[t]; s_w2[t] = fc2w[t]; }
    for (int u = t; u < 8192; u += 256) {
        int c = u >> 7, j = u & 127;
        s_w[c][j] = fc1w[j * 64 + c];
    }
    for (int u = t; u < 8192; u += 256) {
        int c = u >> 7, px = u & 127;
        int p = pbase + px;
        float v = 0.f;
        if (p < NPIX) {
            int b = p / 14161;
            int rem = p - b * 14161;
            int rr = rem / 119;
            int col = rem - rr * 119;
            v = h[((size_t)(b * 64 + c) * 128 + rr) * 128 + col];
        }
        s_hx[c][px] = v;
    }
    __syncthreads();
    int pt = t >> 4, jt = t & 15;
    int px0 = pt * 8, j0 = jt * 8;
    float acc[8][8];
#pragma unroll
    for (int i = 0; i < 8; ++i)
#pragma unroll
        for (int jj = 0; jj < 8; ++jj) acc[i][jj] = s_b1[j0 + jj];
    for (int c = 0; c < 64; ++c) {
        float hv[8], wv[8];
#pragma unroll
        for (int i = 0; i < 8; ++i) hv[i] = s_hx[c][px0 + i];
#pragma unroll
        for (int jj = 0; jj < 8; ++jj) wv[jj] = s_w[c][j0 + jj];
#pragma unroll
        for (int i = 0; i < 8; ++i)
#pragma unroll
            for (int jj = 0; jj < 8; ++jj) acc[i][jj] += hv[i] * wv[jj];
    }
#pragma unroll
    for (int i = 0; i < 8; ++i) {
        float o = 0.f;
#pragma unroll
        for (int jj = 0; jj < 8; ++jj) o += gelu_f(acc[i][jj]) * s_w2[j0 + jj];
        s_red[jt][px0 + i] = o;
    }
    __syncthreads();
    if (t < 128) {
        int p = pbase + t;
        if (p < NPIX) {
            float o = fc2b[0];
#pragma unroll
            for (int q = 0; q < 16; ++q) o += s_red[q][t];
            out[p] = o;
        }
    }
}

extern "C" void kernel_launch(void* const* d_in, const int* in_sizes, int n_in,
                              void* d_out, int out_size, void* d_ws, size_t ws_size,
                              hipStream_t stream) {
    const float* x    = (const float*)d_in[0];
    const float* sw1r = (const float*)d_in[1];
    const float* sw1i = (const float*)d_in[2];
    const float* sw2r = (const float*)d_in[3];
    const float* sw2i = (const float*)d_in[4];
    const float* g1w  = (const float*)d_in[5];
    const float* g1b  = (const float*)d_in[6];
    const float* g2w  = (const float*)d_in[7];
    const float* g2b  = (const float*)d_in[8];
    const float* cw   = (const float*)d_in[9];
    const float* cb   = (const float*)d_in[10];
    const float* fc0w = (const float*)d_in[11];
    const float* fc0b = (const float*)d_in[12];
    const float* fc1w = (const float*)d_in[13];
    const float* fc1b = (const float*)d_in[14];
    const float* fc2w = (const float*)d_in[15];
    const float* fc2b = (const float*)d_in[16];
    float* out = (float*)d_out;

    char* ws = (char*)d_ws;
    const size_t SZ_H   = (size_t)NB * NC * NH * NW * 4;      // 33554432
    const size_t SZ_T   = (size_t)NB * NC * NH * 16 * 8;      // 8388608
    const size_t SZ_XFT = (size_t)NB * NC * 32 * 16 * 8;      // 2097152
    const size_t SZ_F   = SZ_XFT;                             // 2097152
    const size_t SZ_G   = (size_t)NB * NH * 16 * 64 * 8;      // 8388608
    size_t off = 0;
    float2* trig = (float2*)(ws + off); off += 1024;
    float2* wdft = (float2*)(ws + off); off += 2048 * 8;
    float*  hA   = (float*)(ws + off);  off += SZ_H;
    float*  hB   = (float*)(ws + off);  off += SZ_H;
    float2* T    = (float2*)(ws + off); off += SZ_T;
    float2* xft  = (float2*)(ws + off); off += SZ_XFT;
    float2* F    = (float2*)(ws + off); off += SZ_F;
    float2* G    = (float2*)(ws + off); off += SZ_G;
    float*  cr   = (float*)(ws + off);  off += (size_t)NB * NC * 16 * 4;
    float*  hmid = (float*)(ws + off);  off += (size_t)NB * 256 * 4;
    float*  corr = (float*)(ws + off);  off += (size_t)NB * 64 * 4;
    (void)ws_size; (void)in_sizes; (void)n_in; (void)out_size;

    k_trig<<<1, 128, 0, stream>>>(trig);
    k_tab<<<16, 128, 0, stream>>>(wdft);
    k_fc0<<<512, 256, 0, stream>>>(x, fc0w, fc0b, hA);

    float* hcur = hA;
    float* hnxt = hB;
    for (int l = 0; l < 4; ++l) {
        const float* w1r = sw1r + (size_t)l * 1048576;
        const float* w1i = sw1i + (size_t)l * 1048576;
        const float* w2r = sw2r + (size_t)l * 1048576;
        const float* w2i = sw2i + (size_t)l * 1048576;
        const float* g1w_l = g1w + (size_t)l * 524288;
        const float* g1b_l = g1b + l * 256;
        const float* g2w_l = g2w + (size_t)l * 16384;
        const float* g2b_l = g2b + l * 64;
        const float* cw_l  = cw + (size_t)l * 4096;
        const float* cb_l  = cb + l * 64;

        k_cft<<<512, 256, 0, stream>>>(hcur, cr);
        k_mlp1<<<256, 256, 0, stream>>>(cr, g1w_l, g1b_l, hmid);
        k_mlp2<<<64, 256, 0, stream>>>(hmid, g2w_l, g2b_l, corr);
        k_dftw<<<2048, 256, 0, stream>>>(hcur, T, wdft);
        k_dfth<<<512, 512, 0, stream>>>(T, xft, trig);
        k_mix<<<512, 512, 0, stream>>>(xft, w1r, w1i, w2r, w2i, F);
        k_inva<<<256, 256, 0, stream>>>(F, G, trig);
        k_invb<<<1024, 256, 0, stream>>>(G, hcur, cw_l, cb_l, corr, trig, hnxt,
                                         (l < 3) ? 1 : 0);
        float* tmp = hcur; hcur = hnxt; hnxt = tmp;
    }
    // after 4 swaps, hcur == hA holds the final features
    k_head<<<886, 256, 0, stream>>>(hcur, fc1w, fc1b, fc2w, fc2b, out);
}